// Round 2
// baseline (856.910 us; speedup 1.0000x reference)
//
#include <hip/hip_runtime.h>
#include <hip/hip_bf16.h>

typedef __hip_bfloat16 bf16;
typedef __attribute__((ext_vector_type(8))) short short8v;
typedef __attribute__((ext_vector_type(4))) short short4v;
typedef __attribute__((ext_vector_type(4))) float f32x4;

#define MFMA_16x16x32(a, b, c) __builtin_amdgcn_mfma_f32_16x16x32_bf16((a), (b), (c), 0, 0, 0)

constexpr int Bc = 2, Sc = 2048, DMc = 2048, Hc = 16, DLc = 512, DHc = 128;

__device__ __forceinline__ void gload_lds16(const bf16* g, void* lds) {
  __builtin_amdgcn_global_load_lds(
      (const __attribute__((address_space(1))) void*)g,
      (__attribute__((address_space(3))) void*)lds, 16, 0, 0);
}

__device__ __forceinline__ unsigned short bf16bits(float f) {
  return __builtin_bit_cast(unsigned short, __float2bfloat16(f));
}

// ---------------------------------------------------------------------------
// fp32 -> bf16 conversion, vectorized (float4 in, 4x bf16 out)
// ---------------------------------------------------------------------------
__global__ __launch_bounds__(256) void cvt_f32_bf16_kernel(
    const float* __restrict__ in, bf16* __restrict__ out, int n)
{
  int i = (blockIdx.x * 256 + threadIdx.x) * 4;
  const int stride = gridDim.x * 256 * 4;
  for (; i < n; i += stride) {
    float4 v = *(const float4*)(in + i);
    short4v p;
    p[0] = (short)bf16bits(v.x);
    p[1] = (short)bf16bits(v.y);
    p[2] = (short)bf16bits(v.z);
    p[3] = (short)bf16bits(v.w);
    *(short4v*)(out + i) = p;
  }
}

// ---------------------------------------------------------------------------
// Generic 128x128 tile, BK=32, C[M][N] = A[M][K] * BT[N][K], bf16 in,
// fp32 accum. EPI=0: bf16 row-major C. EPI=1: bf16 transposed C^T (8B packed
// stores). EPI=2: fp32 row-major C.
// ---------------------------------------------------------------------------
template<int EPI>
__device__ __forceinline__ void gemm_tile_128(
    const bf16* __restrict__ A, const bf16* __restrict__ BT, void* __restrict__ Cv,
    int K, int ldc, int row0, int col0, bf16* As, bf16* Bs)
{
  const int tid = threadIdx.x;
  const int lane = tid & 63, wid = tid >> 6;
  const int wr = wid >> 1, wc = wid & 1;

  f32x4 acc[4][4] = {};

  // staging: thread t loads 16B: row = t/4 (+64 for 2nd issue), col8 = (t%4)*8
  const int srow = tid >> 2;
  const int scol = (tid & 3) * 8;
  const bf16* Ag = A + (size_t)(row0 + srow) * K + scol;
  const bf16* Bg = BT + (size_t)(col0 + srow) * K + scol;
  char* AsW = (char*)As + wid * 1024;   // wave-uniform LDS dest
  char* BsW = (char*)Bs + wid * 1024;

  const int fr = lane & 15, fk = (lane >> 4) * 8;
  const bf16* aRd = As + (wr * 64 + fr) * 32 + fk;
  const bf16* bRd = Bs + (wc * 64 + fr) * 32 + fk;

  for (int k0 = 0; k0 < K; k0 += 32) {
    gload_lds16(Ag, AsW);
    gload_lds16(Ag + (size_t)64 * K, AsW + 4096);
    gload_lds16(Bg, BsW);
    gload_lds16(Bg + (size_t)64 * K, BsW + 4096);
    Ag += 32; Bg += 32;
    __syncthreads();
    short8v a[4], b[4];
#pragma unroll
    for (int m = 0; m < 4; ++m) a[m] = *(const short8v*)(aRd + m * 16 * 32);
#pragma unroll
    for (int n = 0; n < 4; ++n) b[n] = *(const short8v*)(bRd + n * 16 * 32);
#pragma unroll
    for (int m = 0; m < 4; ++m)
#pragma unroll
      for (int n = 0; n < 4; ++n)
        acc[m][n] = MFMA_16x16x32(a[m], b[n], acc[m][n]);
    __syncthreads();
  }

  const int crow = (lane >> 4) * 4, ccol = lane & 15;
  if (EPI == 0) {
    bf16* C = (bf16*)Cv;
#pragma unroll
    for (int m = 0; m < 4; ++m)
#pragma unroll
      for (int n = 0; n < 4; ++n) {
        bf16* Cp = C + (size_t)(row0 + wr * 64 + m * 16 + crow) * ldc
                     + col0 + wc * 64 + n * 16 + ccol;
#pragma unroll
        for (int r = 0; r < 4; ++r)
          Cp[(size_t)r * ldc] = __float2bfloat16(acc[m][n][r]);
      }
  } else if (EPI == 1) {
    bf16* C = (bf16*)Cv;
#pragma unroll
    for (int m = 0; m < 4; ++m)
#pragma unroll
      for (int n = 0; n < 4; ++n) {
        short4v pk;
#pragma unroll
        for (int r = 0; r < 4; ++r)
          pk[r] = (short)bf16bits(acc[m][n][r]);
        bf16* Cp = C + (size_t)(col0 + wc * 64 + n * 16 + ccol) * ldc
                     + row0 + wr * 64 + m * 16 + crow;
        *(short4v*)Cp = pk;
      }
  } else {
    float* C = (float*)Cv;
#pragma unroll
    for (int m = 0; m < 4; ++m)
#pragma unroll
      for (int n = 0; n < 4; ++n) {
        float* Cp = C + (size_t)(row0 + wr * 64 + m * 16 + crow) * ldc
                      + col0 + wc * 64 + n * 16 + ccol;
#pragma unroll
        for (int r = 0; r < 4; ++r)
          Cp[(size_t)r * ldc] = acc[m][n][r];
      }
  }
}

template<int EPI>
__global__ __launch_bounds__(256) void gemm_bt_kernel(
    const bf16* __restrict__ A, const bf16* __restrict__ BT, void* __restrict__ C,
    int K, int N)
{
  __shared__ bf16 As[128 * 32];
  __shared__ bf16 Bs[128 * 32];
  gemm_tile_128<EPI>(A, BT, C, K, N, blockIdx.y * 128, blockIdx.x * 128, As, Bs);
}

// K/V up-projection: per z=(b*H+h): out = Ckv[b] (SxDL) @ W[h]^T (DHxDL)
// EPI=0 -> K stored (z, S, DH); EPI=1 -> V stored transposed (z, DH, S)
template<int EPI>
__global__ __launch_bounds__(256) void upproj_kernel(
    const bf16* __restrict__ Ckv, const bf16* __restrict__ W, bf16* __restrict__ Out)
{
  __shared__ bf16 As[128 * 32];
  __shared__ bf16 Bs[128 * 32];
  const int z = blockIdx.y, b = z / Hc, h = z % Hc;
  const bf16* A = Ckv + (size_t)b * Sc * DLc;
  const bf16* BT = W + (size_t)h * DHc * DLc;
  if (EPI == 0) {
    bf16* C = Out + (size_t)z * Sc * DHc;
    gemm_tile_128<0>(A, BT, C, DLc, DHc, blockIdx.x * 128, 0, As, Bs);
  } else {
    bf16* C = Out + (size_t)z * DHc * Sc;
    gemm_tile_128<1>(A, BT, C, DLc, Sc, blockIdx.x * 128, 0, As, Bs);
  }
}

// ---------------------------------------------------------------------------
// Flash attention. Q: (B*S, DM) cols h*128+d. Kup: (B*H, S, DH).
// VT: (B*H, DH, S). O: (B*S, DM) bf16. 4 waves/block, 16 q-rows/wave,
// KV tile 64.
// ---------------------------------------------------------------------------
__global__ __launch_bounds__(256) void mla_attn_kernel(
    const bf16* __restrict__ Q, const bf16* __restrict__ Kup,
    const bf16* __restrict__ VT, bf16* __restrict__ O)
{
  __shared__ bf16 Pl[4][16][72];   // per-wave P tile, padded (conflict-free 8B reads)
  const int tid = threadIdx.x, lane = tid & 63, wid = tid >> 6;
  const int h = blockIdx.y, b = blockIdx.z;
  const int q0 = blockIdx.x * 64 + wid * 16;
  const int fr = lane & 15, fg = lane >> 4;

  // resident Q A-fragments: lane holds Q[q0 + fr][kf*32 + fg*8 + j]
  const bf16* Qp = Q + (size_t)(b * Sc + q0 + fr) * DMc + h * DHc + fg * 8;
  short8v qf[4];
#pragma unroll
  for (int kf = 0; kf < 4; ++kf) qf[kf] = *(const short8v*)(Qp + kf * 32);

  const bf16* Kb = Kup + (size_t)(b * Hc + h) * Sc * DHc;   // K[t][d]
  const bf16* Vb = VT + (size_t)(b * Hc + h) * DHc * Sc;    // VT[d][t]

  f32x4 oacc[8] = {};
  float m_r[4], l_r[4];
#pragma unroll
  for (int r = 0; r < 4; ++r) { m_r[r] = -1e30f; l_r[r] = 0.f; }
  const float scale = 0.08838834764831845f;   // 1/sqrt(128)

  for (int t0 = 0; t0 < Sc; t0 += 64) {
    // ---- QK^T: S tile 16x64, D-layout row=fg*4+r (q), col=fr within nf ----
    f32x4 sacc[4] = {};
#pragma unroll
    for (int nf = 0; nf < 4; ++nf) {
      const bf16* Kr = Kb + (size_t)(t0 + nf * 16 + fr) * DHc + fg * 8;
#pragma unroll
      for (int kf = 0; kf < 4; ++kf) {
        short8v kfrag = *(const short8v*)(Kr + kf * 32);
        sacc[nf] = MFMA_16x16x32(qf[kf], kfrag, sacc[nf]);
      }
    }
#pragma unroll
    for (int nf = 0; nf < 4; ++nf) sacc[nf] *= scale;

    // ---- online softmax ----
    float rmax[4];
#pragma unroll
    for (int r = 0; r < 4; ++r)
      rmax[r] = fmaxf(fmaxf(sacc[0][r], sacc[1][r]), fmaxf(sacc[2][r], sacc[3][r]));
#pragma unroll
    for (int r = 0; r < 4; ++r) {
#pragma unroll
      for (int mk = 1; mk < 16; mk <<= 1)
        rmax[r] = fmaxf(rmax[r], __shfl_xor(rmax[r], mk, 64));
    }
    float corr[4];
#pragma unroll
    for (int r = 0; r < 4; ++r) {
      float mnew = fmaxf(m_r[r], rmax[r]);
      corr[r] = __expf(m_r[r] - mnew);
      m_r[r] = mnew;
      l_r[r] *= corr[r];
    }
#pragma unroll
    for (int nf = 0; nf < 4; ++nf) {
#pragma unroll
      for (int r = 0; r < 4; ++r) {
        float p = __expf(sacc[nf][r] - m_r[r]);
        l_r[r] += p;
        Pl[wid][fg * 4 + r][nf * 16 + fr] = __float2bfloat16(p);
      }
    }
    f32x4 corrv;
#pragma unroll
    for (int r = 0; r < 4; ++r) corrv[r] = corr[r];
#pragma unroll
    for (int df = 0; df < 8; ++df) oacc[df] *= corrv;

    // wave-local LDS round trip: D-layout P -> A-layout P
    asm volatile("s_waitcnt lgkmcnt(0)" ::: "memory");
    __builtin_amdgcn_sched_barrier(0);

    short8v pa[2];
#pragma unroll
    for (int tf = 0; tf < 2; ++tf) {
      const bf16* pr = &Pl[wid][fr][tf * 32 + fg * 8];
      short4v lo = *(const short4v*)pr;
      short4v hi = *(const short4v*)(pr + 4);
      pa[tf] = __builtin_shufflevector(lo, hi, 0, 1, 2, 3, 4, 5, 6, 7);
    }

    // ---- PV: O += P(16x64) * V(64x128), V from VT rows (contiguous) ----
#pragma unroll
    for (int tf = 0; tf < 2; ++tf) {
#pragma unroll
      for (int df = 0; df < 8; ++df) {
        const bf16* Vr = Vb + (size_t)(df * 16 + fr) * Sc + t0 + tf * 32 + fg * 8;
        short8v vfrag = *(const short8v*)Vr;
        oacc[df] = MFMA_16x16x32(pa[tf], vfrag, oacc[df]);
      }
    }
  }

  // final denominator reduce across the 16 lanes of each row group
#pragma unroll
  for (int r = 0; r < 4; ++r) {
#pragma unroll
    for (int mk = 1; mk < 16; mk <<= 1)
      l_r[r] += __shfl_xor(l_r[r], mk, 64);
  }
  float inv[4];
#pragma unroll
  for (int r = 0; r < 4; ++r) inv[r] = 1.f / l_r[r];

  bf16* Op = O + (size_t)(b * Sc + q0 + fg * 4) * DMc + h * DHc + fr;
#pragma unroll
  for (int df = 0; df < 8; ++df)
#pragma unroll
    for (int r = 0; r < 4; ++r)
      Op[(size_t)r * DMc + df * 16] = __float2bfloat16(oacc[df][r] * inv[r]);
}

// ---------------------------------------------------------------------------
extern "C" void kernel_launch(void* const* d_in, const int* in_sizes, int n_in,
                              void* d_out, int out_size, void* d_ws, size_t ws_size,
                              hipStream_t stream)
{
  const float* x    = (const float*)d_in[0];
  const float* Wq   = (const float*)d_in[1];
  const float* Wdkv = (const float*)d_in[2];
  const float* Wuk  = (const float*)d_in[3];
  const float* Wuv  = (const float*)d_in[4];
  const float* Wo   = (const float*)d_in[5];
  float* out = (float*)d_out;

  char* ws = (char*)d_ws;
  // byte offsets (AO overlays xb: xb dead after Ckv gemm, AO written later)
  bf16* Qb    = (bf16*)(ws + 0);              // 16 MB
  bf16* Kup   = (bf16*)(ws + 16777216);       // 16 MB
  bf16* VTb   = (bf16*)(ws + 33554432);       // 16 MB
  bf16* xb    = (bf16*)(ws + 50331648);       // 16 MB
  bf16* AO    = (bf16*)(ws + 50331648);       // overlay
  bf16* Ck    = (bf16*)(ws + 67108864);       //  4 MB
  bf16* Wqb   = (bf16*)(ws + 71303168);       //  8 MB
  bf16* Wdkvb = (bf16*)(ws + 79691776);       //  2 MB
  bf16* Wukb  = (bf16*)(ws + 81788928);       //  2 MB
  bf16* Wuvb  = (bf16*)(ws + 83886080);       //  2 MB
  bf16* Wob   = (bf16*)(ws + 85983232);       //  8 MB

  dim3 blk(256, 1, 1);

  // fp32 -> bf16 conversions
  const int nx = Bc * Sc * DMc, nwq = DMc * DMc, nwd = DLc * DMc,
            nwu = Hc * DHc * DLc;
  cvt_f32_bf16_kernel<<<1024, blk, 0, stream>>>(x, xb, nx);
  cvt_f32_bf16_kernel<<<1024, blk, 0, stream>>>(Wq, Wqb, nwq);
  cvt_f32_bf16_kernel<<<512, blk, 0, stream>>>(Wdkv, Wdkvb, nwd);
  cvt_f32_bf16_kernel<<<512, blk, 0, stream>>>(Wuk, Wukb, nwu);
  cvt_f32_bf16_kernel<<<512, blk, 0, stream>>>(Wuv, Wuvb, nwu);
  cvt_f32_bf16_kernel<<<1024, blk, 0, stream>>>(Wo, Wob, nwq);

  // Q = x @ Wq^T            (M=4096, N=2048, K=2048)
  gemm_bt_kernel<0><<<dim3(DMc / 128, (Bc * Sc) / 128), blk, 0, stream>>>(xb, Wqb, Qb, DMc, DMc);
  // Ckv = x @ Wdkv^T        (M=4096, N=512, K=2048)
  gemm_bt_kernel<0><<<dim3(DLc / 128, (Bc * Sc) / 128), blk, 0, stream>>>(xb, Wdkvb, Ck, DMc, DLc);
  // K up-projection         (per (b,h): 2048x512 @ 512x128)
  upproj_kernel<0><<<dim3(Sc / 128, Bc * Hc), blk, 0, stream>>>(Ck, Wukb, Kup);
  // V up-projection, transposed store
  upproj_kernel<1><<<dim3(Sc / 128, Bc * Hc), blk, 0, stream>>>(Ck, Wuvb, VTb);
  // attention
  mla_attn_kernel<<<dim3(Sc / 64, Hc, Bc), blk, 0, stream>>>(Qb, Kup, VTb, AO);
  // out = AO @ Wo^T         (M=4096, N=2048, K=2048), fp32 out
  gemm_bt_kernel<2><<<dim3(DMc / 128, (Bc * Sc) / 128), blk, 0, stream>>>(AO, Wob, out, DMc, DMc);
}

// Round 4
// 336.014 us; speedup vs baseline: 2.5502x; 2.5502x over previous
//
#include <hip/hip_runtime.h>
#include <hip/hip_bf16.h>

typedef __hip_bfloat16 bf16;
typedef __attribute__((ext_vector_type(8))) short short8v;
typedef __attribute__((ext_vector_type(4))) short short4v;
typedef __attribute__((ext_vector_type(4))) float f32x4;

#define MFMA_16x16x32(a, b, c) __builtin_amdgcn_mfma_f32_16x16x32_bf16((a), (b), (c), 0, 0, 0)

constexpr int Bc = 2, Sc = 2048, DMc = 2048, Hc = 16, DLc = 512, DHc = 128;

__device__ __forceinline__ void gload_lds16(const bf16* g, void* lds) {
  __builtin_amdgcn_global_load_lds(
      (const __attribute__((address_space(1))) void*)g,
      (__attribute__((address_space(3))) void*)lds, 16, 0, 0);
}

__device__ __forceinline__ unsigned short bf16bits(float f) {
  return __builtin_bit_cast(unsigned short, __float2bfloat16(f));
}

// ---------------------------------------------------------------------------
// fp32 -> bf16 conversion, vectorized
// ---------------------------------------------------------------------------
__global__ __launch_bounds__(256) void cvt_f32_bf16_kernel(
    const float* __restrict__ in, bf16* __restrict__ out, int n)
{
  int i = (blockIdx.x * 256 + threadIdx.x) * 4;
  const int stride = gridDim.x * 256 * 4;
  for (; i < n; i += stride) {
    float4 v = *(const float4*)(in + i);
    short4v p;
    p[0] = (short)bf16bits(v.x);
    p[1] = (short)bf16bits(v.y);
    p[2] = (short)bf16bits(v.z);
    p[3] = (short)bf16bits(v.w);
    *(short4v*)(out + i) = p;
  }
}

// ---------------------------------------------------------------------------
// Generic 128x128 tile GEMM, BK=32, C = A * BT^T. EPI: 0 bf16 C, 1 bf16 C^T,
// 2 fp32 C.
// ---------------------------------------------------------------------------
template<int EPI>
__device__ __forceinline__ void gemm_tile_128(
    const bf16* __restrict__ A, const bf16* __restrict__ BT, void* __restrict__ Cv,
    int K, int ldc, int row0, int col0, bf16* As, bf16* Bs)
{
  const int tid = threadIdx.x;
  const int lane = tid & 63, wid = tid >> 6;
  const int wr = wid >> 1, wc = wid & 1;

  f32x4 acc[4][4] = {};

  const int srow = tid >> 2;
  const int scol = (tid & 3) * 8;
  const bf16* Ag = A + (size_t)(row0 + srow) * K + scol;
  const bf16* Bg = BT + (size_t)(col0 + srow) * K + scol;
  char* AsW = (char*)As + wid * 1024;
  char* BsW = (char*)Bs + wid * 1024;

  const int fr = lane & 15, fk = (lane >> 4) * 8;
  const bf16* aRd = As + (wr * 64 + fr) * 32 + fk;
  const bf16* bRd = Bs + (wc * 64 + fr) * 32 + fk;

  for (int k0 = 0; k0 < K; k0 += 32) {
    gload_lds16(Ag, AsW);
    gload_lds16(Ag + (size_t)64 * K, AsW + 4096);
    gload_lds16(Bg, BsW);
    gload_lds16(Bg + (size_t)64 * K, BsW + 4096);
    Ag += 32; Bg += 32;
    __syncthreads();
    short8v a[4], b[4];
#pragma unroll
    for (int m = 0; m < 4; ++m) a[m] = *(const short8v*)(aRd + m * 16 * 32);
#pragma unroll
    for (int n = 0; n < 4; ++n) b[n] = *(const short8v*)(bRd + n * 16 * 32);
#pragma unroll
    for (int m = 0; m < 4; ++m)
#pragma unroll
      for (int n = 0; n < 4; ++n)
        acc[m][n] = MFMA_16x16x32(a[m], b[n], acc[m][n]);
    __syncthreads();
  }

  const int crow = (lane >> 4) * 4, ccol = lane & 15;
  if (EPI == 0) {
    bf16* C = (bf16*)Cv;
#pragma unroll
    for (int m = 0; m < 4; ++m)
#pragma unroll
      for (int n = 0; n < 4; ++n) {
        bf16* Cp = C + (size_t)(row0 + wr * 64 + m * 16 + crow) * ldc
                     + col0 + wc * 64 + n * 16 + ccol;
#pragma unroll
        for (int r = 0; r < 4; ++r)
          Cp[(size_t)r * ldc] = __float2bfloat16(acc[m][n][r]);
      }
  } else if (EPI == 1) {
    bf16* C = (bf16*)Cv;
#pragma unroll
    for (int m = 0; m < 4; ++m)
#pragma unroll
      for (int n = 0; n < 4; ++n) {
        short4v pk;
#pragma unroll
        for (int r = 0; r < 4; ++r)
          pk[r] = (short)bf16bits(acc[m][n][r]);
        bf16* Cp = C + (size_t)(col0 + wc * 64 + n * 16 + ccol) * ldc
                     + row0 + wr * 64 + m * 16 + crow;
        *(short4v*)Cp = pk;
      }
  } else {
    float* C = (float*)Cv;
#pragma unroll
    for (int m = 0; m < 4; ++m)
#pragma unroll
      for (int n = 0; n < 4; ++n) {
        float* Cp = C + (size_t)(row0 + wr * 64 + m * 16 + crow) * ldc
                      + col0 + wc * 64 + n * 16 + ccol;
#pragma unroll
        for (int r = 0; r < 4; ++r)
          Cp[(size_t)r * ldc] = acc[m][n][r];
      }
  }
}

template<int EPI>
__global__ __launch_bounds__(256) void gemm_bt_kernel(
    const bf16* __restrict__ A, const bf16* __restrict__ BT, void* __restrict__ C,
    int K, int N)
{
  __shared__ bf16 As[128 * 32];
  __shared__ bf16 Bs[128 * 32];
  gemm_tile_128<EPI>(A, BT, C, K, N, blockIdx.y * 128, blockIdx.x * 128, As, Bs);
}

template<int EPI>
__global__ __launch_bounds__(256) void upproj_kernel(
    const bf16* __restrict__ Ckv, const bf16* __restrict__ W, bf16* __restrict__ Out)
{
  __shared__ bf16 As[128 * 32];
  __shared__ bf16 Bs[128 * 32];
  const int z = blockIdx.y, b = z / Hc, h = z % Hc;
  const bf16* A = Ckv + (size_t)b * Sc * DLc;
  const bf16* BT = W + (size_t)h * DHc * DLc;
  if (EPI == 0) {
    bf16* C = Out + (size_t)z * Sc * DHc;
    gemm_tile_128<0>(A, BT, C, DLc, DHc, blockIdx.x * 128, 0, As, Bs);
  } else {
    bf16* C = Out + (size_t)z * DHc * Sc;
    gemm_tile_128<1>(A, BT, C, DLc, Sc, blockIdx.x * 128, 0, As, Bs);
  }
}

// ---------------------------------------------------------------------------
// Flash attention, pipelined LDS-staged K/V (double-buffered, XOR-swizzled).
// 8 waves/block, 32 q-rows/wave (block = 256 q-rows). KV tile = 64.
// Staging: linear LDS dest (global_load_lds requirement), inverse-swizzled
// global source, swizzled ds_read (rule #21: both-sides-or-neither).
// K tile 16 KB = 2 issues x (512 thr x 16 B); same for VT tile.
// ---------------------------------------------------------------------------
constexpr int KVB = 64;
constexpr int NTT = Sc / KVB;   // 32 tiles

__global__ __launch_bounds__(512, 2) void mla_attn_kernel(
    const bf16* __restrict__ Q, const bf16* __restrict__ Kup,
    const bf16* __restrict__ VT, bf16* __restrict__ O)
{
  __shared__ bf16 Ks[2][KVB * DHc];    // 16 KB each
  __shared__ bf16 Vs[2][DHc * KVB];    // 16 KB each
  __shared__ bf16 Pl[8][32][72];       // per-wave P tile (36 KB), 144B stride

  const int tid = threadIdx.x, lane = tid & 63, wid = tid >> 6;
  const int h = blockIdx.y, b = blockIdx.z;
  const int q0 = blockIdx.x * 256 + wid * 32;
  const int fr = lane & 15, fg = lane >> 4;

  // resident Q fragments: 2 m-subtiles x 4 k-frags
  const bf16* Qp = Q + (size_t)(b * Sc + q0 + fr) * DMc + h * DHc + fg * 8;
  short8v qf[2][4];
#pragma unroll
  for (int mi = 0; mi < 2; ++mi)
#pragma unroll
    for (int kf = 0; kf < 4; ++kf)
      qf[mi][kf] = *(const short8v*)(Qp + (size_t)mi * 16 * DMc + kf * 32);

  const bf16* Kb = Kup + (size_t)(b * Hc + h) * Sc * DHc;   // K[t][d]
  const bf16* Vb = VT + (size_t)(b * Hc + h) * DHc * Sc;    // VT[d][t]

  // staging addresses (inverse-swizzled global sources; LDS dest linear).
  // K issue j (j=0,1): LDS byte = wid*1024 + j*8192 + lane*16
  //   -> row = wid*4 + fg + j*32, colByte = fr*16; row&7 indep of j.
  const int krow = wid * 4 + fg;
  const int kcolB = (fr * 16) ^ ((krow & 7) << 4);
  const bf16* kg = Kb + (size_t)krow * DHc + (kcolB >> 1);
  // V issue j: row d = wid*8 + (lane>>3) + j*64, colByte = (lane&7)*16
  const int vrow = wid * 8 + (lane >> 3);
  const int vcolB = ((lane & 7) * 16) ^ ((lane >> 3) << 4);
  const bf16* vg = Vb + (size_t)vrow * Sc + (vcolB >> 1);

  auto STAGE = [&](int buf, int t0) {
    char* kd = (char*)(&Ks[buf][0]) + wid * 1024;
    const bf16* kp = kg + (size_t)t0 * DHc;
    gload_lds16(kp, kd);
    gload_lds16(kp + (size_t)32 * DHc, kd + 8192);
    char* vd = (char*)(&Vs[buf][0]) + wid * 1024;
    const bf16* vp = vg + t0;
    gload_lds16(vp, vd);
    gload_lds16(vp + (size_t)64 * Sc, vd + 8192);
  };

  f32x4 oacc[2][8] = {};
  float m_r[2][4], l_r[2][4];
#pragma unroll
  for (int mi = 0; mi < 2; ++mi)
#pragma unroll
    for (int r = 0; r < 4; ++r) { m_r[mi][r] = -1e30f; l_r[mi][r] = 0.f; }
  const float SCL2 = 0.12751650f;   // (1/sqrt(128)) * log2(e)

  STAGE(0, 0);
  int cur = 0;

  for (int it = 0; it < NTT; ++it) {
    if (it + 1 < NTT) {
      STAGE(cur ^ 1, (it + 1) * KVB);
      asm volatile("s_waitcnt vmcnt(4)" ::: "memory");
    } else {
      asm volatile("s_waitcnt vmcnt(0)" ::: "memory");
    }
    __builtin_amdgcn_s_barrier();
    asm volatile("" ::: "memory");

    // ---- QK^T: each K frag feeds both m-subtiles ----
    f32x4 sacc[2][4] = {};
#pragma unroll
    for (int nf = 0; nf < 4; ++nf) {
#pragma unroll
      for (int kf = 0; kf < 4; ++kf) {
        const bf16* kr = &Ks[cur][(nf * 16 + fr) * 128 +
                                  (((kf * 64 + fg * 16) ^ ((fr & 7) << 4)) >> 1)];
        short8v kfrag = *(const short8v*)kr;
        sacc[0][nf] = MFMA_16x16x32(qf[0][kf], kfrag, sacc[0][nf]);
        sacc[1][nf] = MFMA_16x16x32(qf[1][kf], kfrag, sacc[1][nf]);
      }
    }

    // ---- online softmax (exp2 domain, scale folded) ----
#pragma unroll
    for (int mi = 0; mi < 2; ++mi) {
      float rmax[4];
#pragma unroll
      for (int r = 0; r < 4; ++r)
        rmax[r] = fmaxf(fmaxf(sacc[mi][0][r], sacc[mi][1][r]),
                        fmaxf(sacc[mi][2][r], sacc[mi][3][r]));
#pragma unroll
      for (int r = 0; r < 4; ++r)
#pragma unroll
        for (int mk = 1; mk < 16; mk <<= 1)
          rmax[r] = fmaxf(rmax[r], __shfl_xor(rmax[r], mk, 64));
      f32x4 corrv;
#pragma unroll
      for (int r = 0; r < 4; ++r) {
        float mnew = fmaxf(m_r[mi][r], rmax[r]);
        float c = exp2f((m_r[mi][r] - mnew) * SCL2);
        m_r[mi][r] = mnew;
        l_r[mi][r] *= c;
        corrv[r] = c;
      }
#pragma unroll
      for (int nf = 0; nf < 4; ++nf)
#pragma unroll
        for (int r = 0; r < 4; ++r) {
          float p = exp2f((sacc[mi][nf][r] - m_r[mi][r]) * SCL2);
          l_r[mi][r] += p;
          Pl[wid][mi * 16 + fg * 4 + r][nf * 16 + fr] = __float2bfloat16(p);
        }
#pragma unroll
      for (int df = 0; df < 8; ++df) oacc[mi][df] *= corrv;
    }

    // wave-local D-layout -> A-layout P roundtrip
    asm volatile("s_waitcnt lgkmcnt(0)" ::: "memory");
    __builtin_amdgcn_sched_barrier(0);

    short8v pa[2][2];
#pragma unroll
    for (int mi = 0; mi < 2; ++mi)
#pragma unroll
      for (int tf = 0; tf < 2; ++tf)
        pa[mi][tf] = *(const short8v*)(&Pl[wid][mi * 16 + fr][tf * 32 + fg * 8]);

    // ---- PV: O += P(32x64) * V(64x128) ----
#pragma unroll
    for (int tf = 0; tf < 2; ++tf) {
#pragma unroll
      for (int df = 0; df < 8; ++df) {
        const bf16* vr = &Vs[cur][(df * 16 + fr) * 64 +
                                  (((tf * 64 + fg * 16) ^ ((fr & 7) << 4)) >> 1)];
        short8v vfrag = *(const short8v*)vr;
        oacc[0][df] = MFMA_16x16x32(pa[0][tf], vfrag, oacc[0][df]);
        oacc[1][df] = MFMA_16x16x32(pa[1][tf], vfrag, oacc[1][df]);
      }
    }

    __builtin_amdgcn_s_barrier();
    asm volatile("" ::: "memory");
    cur ^= 1;
  }

  // epilogue: denominator reduce + store
#pragma unroll
  for (int mi = 0; mi < 2; ++mi) {
    float inv[4];
#pragma unroll
    for (int r = 0; r < 4; ++r) {
      float l = l_r[mi][r];
#pragma unroll
      for (int mk = 1; mk < 16; mk <<= 1)
        l += __shfl_xor(l, mk, 64);
      inv[r] = 1.f / l;
    }
    bf16* Op = O + (size_t)(b * Sc + q0 + mi * 16 + fg * 4) * DMc + h * DHc + fr;
#pragma unroll
    for (int df = 0; df < 8; ++df)
#pragma unroll
      for (int r = 0; r < 4; ++r)
        Op[(size_t)r * DMc + df * 16] = __float2bfloat16(oacc[mi][df][r] * inv[r]);
  }
}

// ---------------------------------------------------------------------------
extern "C" void kernel_launch(void* const* d_in, const int* in_sizes, int n_in,
                              void* d_out, int out_size, void* d_ws, size_t ws_size,
                              hipStream_t stream)
{
  const float* x    = (const float*)d_in[0];
  const float* Wq   = (const float*)d_in[1];
  const float* Wdkv = (const float*)d_in[2];
  const float* Wuk  = (const float*)d_in[3];
  const float* Wuv  = (const float*)d_in[4];
  const float* Wo   = (const float*)d_in[5];
  float* out = (float*)d_out;

  char* ws = (char*)d_ws;
  bf16* Qb    = (bf16*)(ws + 0);              // 16 MB
  bf16* Kup   = (bf16*)(ws + 16777216);       // 16 MB
  bf16* VTb   = (bf16*)(ws + 33554432);       // 16 MB
  bf16* xb    = (bf16*)(ws + 50331648);       // 16 MB
  bf16* AO    = (bf16*)(ws + 50331648);       // overlay (xb dead by then)
  bf16* Ck    = (bf16*)(ws + 67108864);       //  4 MB
  bf16* Wqb   = (bf16*)(ws + 71303168);       //  8 MB
  bf16* Wdkvb = (bf16*)(ws + 79691776);       //  2 MB
  bf16* Wukb  = (bf16*)(ws + 81788928);       //  2 MB
  bf16* Wuvb  = (bf16*)(ws + 83886080);       //  2 MB
  bf16* Wob   = (bf16*)(ws + 85983232);       //  8 MB

  dim3 blk(256, 1, 1);

  const int nx = Bc * Sc * DMc, nwq = DMc * DMc, nwd = DLc * DMc,
            nwu = Hc * DHc * DLc;
  cvt_f32_bf16_kernel<<<1024, blk, 0, stream>>>(x, xb, nx);
  cvt_f32_bf16_kernel<<<1024, blk, 0, stream>>>(Wq, Wqb, nwq);
  cvt_f32_bf16_kernel<<<512, blk, 0, stream>>>(Wdkv, Wdkvb, nwd);
  cvt_f32_bf16_kernel<<<512, blk, 0, stream>>>(Wuk, Wukb, nwu);
  cvt_f32_bf16_kernel<<<512, blk, 0, stream>>>(Wuv, Wuvb, nwu);
  cvt_f32_bf16_kernel<<<1024, blk, 0, stream>>>(Wo, Wob, nwq);

  gemm_bt_kernel<0><<<dim3(DMc / 128, (Bc * Sc) / 128), blk, 0, stream>>>(xb, Wqb, Qb, DMc, DMc);
  gemm_bt_kernel<0><<<dim3(DLc / 128, (Bc * Sc) / 128), blk, 0, stream>>>(xb, Wdkvb, Ck, DMc, DLc);
  upproj_kernel<0><<<dim3(Sc / 128, Bc * Hc), blk, 0, stream>>>(Ck, Wukb, Kup);
  upproj_kernel<1><<<dim3(Sc / 128, Bc * Hc), blk, 0, stream>>>(Ck, Wuvb, VTb);

  mla_attn_kernel<<<dim3(Sc / 256, Hc, Bc), dim3(512, 1, 1), 0, stream>>>(Qb, Kup, VTb, AO);

  gemm_bt_kernel<2><<<dim3(DMc / 128, (Bc * Sc) / 128), blk, 0, stream>>>(AO, Wob, out, DMc, DMc);
}

// Round 5
// 313.578 us; speedup vs baseline: 2.7327x; 1.0715x over previous
//
#include <hip/hip_runtime.h>
#include <hip/hip_bf16.h>

typedef __hip_bfloat16 bf16;
typedef __attribute__((ext_vector_type(8))) short short8v;
typedef __attribute__((ext_vector_type(4))) short short4v;
typedef __attribute__((ext_vector_type(4))) float f32x4;

#define MFMA_16x16x32(a, b, c) __builtin_amdgcn_mfma_f32_16x16x32_bf16((a), (b), (c), 0, 0, 0)

constexpr int Bc = 2, Sc = 2048, DMc = 2048, Hc = 16, DLc = 512, DHc = 128;

__device__ __forceinline__ void gload_lds16(const bf16* g, void* lds) {
  __builtin_amdgcn_global_load_lds(
      (const __attribute__((address_space(1))) void*)g,
      (__attribute__((address_space(3))) void*)lds, 16, 0, 0);
}

__device__ __forceinline__ unsigned short bf16bits(float f) {
  return __builtin_bit_cast(unsigned short, __float2bfloat16(f));
}

// ---------------------------------------------------------------------------
// fp32 -> bf16 conversion, vectorized
// ---------------------------------------------------------------------------
__global__ __launch_bounds__(256) void cvt_f32_bf16_kernel(
    const float* __restrict__ in, bf16* __restrict__ out, int n)
{
  int i = (blockIdx.x * 256 + threadIdx.x) * 4;
  const int stride = gridDim.x * 256 * 4;
  for (; i < n; i += stride) {
    float4 v = *(const float4*)(in + i);
    short4v p;
    p[0] = (short)bf16bits(v.x);
    p[1] = (short)bf16bits(v.y);
    p[2] = (short)bf16bits(v.z);
    p[3] = (short)bf16bits(v.w);
    *(short4v*)(out + i) = p;
  }
}

// ---------------------------------------------------------------------------
// Generic 128x128 tile GEMM, BK=32, C = A * BT^T. EPI: 0 bf16 C, 1 bf16 C^T,
// 2 fp32 C.
// ---------------------------------------------------------------------------
template<int EPI>
__device__ __forceinline__ void gemm_tile_128(
    const bf16* __restrict__ A, const bf16* __restrict__ BT, void* __restrict__ Cv,
    int K, int ldc, int row0, int col0, bf16* As, bf16* Bs)
{
  const int tid = threadIdx.x;
  const int lane = tid & 63, wid = tid >> 6;
  const int wr = wid >> 1, wc = wid & 1;

  f32x4 acc[4][4] = {};

  const int srow = tid >> 2;
  const int scol = (tid & 3) * 8;
  const bf16* Ag = A + (size_t)(row0 + srow) * K + scol;
  const bf16* Bg = BT + (size_t)(col0 + srow) * K + scol;
  char* AsW = (char*)As + wid * 1024;
  char* BsW = (char*)Bs + wid * 1024;

  const int fr = lane & 15, fk = (lane >> 4) * 8;
  const bf16* aRd = As + (wr * 64 + fr) * 32 + fk;
  const bf16* bRd = Bs + (wc * 64 + fr) * 32 + fk;

  for (int k0 = 0; k0 < K; k0 += 32) {
    gload_lds16(Ag, AsW);
    gload_lds16(Ag + (size_t)64 * K, AsW + 4096);
    gload_lds16(Bg, BsW);
    gload_lds16(Bg + (size_t)64 * K, BsW + 4096);
    Ag += 32; Bg += 32;
    __syncthreads();
    short8v a[4], b[4];
#pragma unroll
    for (int m = 0; m < 4; ++m) a[m] = *(const short8v*)(aRd + m * 16 * 32);
#pragma unroll
    for (int n = 0; n < 4; ++n) b[n] = *(const short8v*)(bRd + n * 16 * 32);
#pragma unroll
    for (int m = 0; m < 4; ++m)
#pragma unroll
      for (int n = 0; n < 4; ++n)
        acc[m][n] = MFMA_16x16x32(a[m], b[n], acc[m][n]);
    __syncthreads();
  }

  const int crow = (lane >> 4) * 4, ccol = lane & 15;
  if (EPI == 0) {
    bf16* C = (bf16*)Cv;
#pragma unroll
    for (int m = 0; m < 4; ++m)
#pragma unroll
      for (int n = 0; n < 4; ++n) {
        bf16* Cp = C + (size_t)(row0 + wr * 64 + m * 16 + crow) * ldc
                     + col0 + wc * 64 + n * 16 + ccol;
#pragma unroll
        for (int r = 0; r < 4; ++r)
          Cp[(size_t)r * ldc] = __float2bfloat16(acc[m][n][r]);
      }
  } else if (EPI == 1) {
    bf16* C = (bf16*)Cv;
#pragma unroll
    for (int m = 0; m < 4; ++m)
#pragma unroll
      for (int n = 0; n < 4; ++n) {
        short4v pk;
#pragma unroll
        for (int r = 0; r < 4; ++r)
          pk[r] = (short)bf16bits(acc[m][n][r]);
        bf16* Cp = C + (size_t)(col0 + wc * 64 + n * 16 + ccol) * ldc
                     + row0 + wr * 64 + m * 16 + crow;
        *(short4v*)Cp = pk;
      }
  } else {
    float* C = (float*)Cv;
#pragma unroll
    for (int m = 0; m < 4; ++m)
#pragma unroll
      for (int n = 0; n < 4; ++n) {
        float* Cp = C + (size_t)(row0 + wr * 64 + m * 16 + crow) * ldc
                      + col0 + wc * 64 + n * 16 + ccol;
#pragma unroll
        for (int r = 0; r < 4; ++r)
          Cp[(size_t)r * ldc] = acc[m][n][r];
      }
  }
}

template<int EPI>
__global__ __launch_bounds__(256) void gemm_bt_kernel(
    const bf16* __restrict__ A, const bf16* __restrict__ BT, void* __restrict__ C,
    int K, int N)
{
  __shared__ bf16 As[128 * 32];
  __shared__ bf16 Bs[128 * 32];
  gemm_tile_128<EPI>(A, BT, C, K, N, blockIdx.y * 128, blockIdx.x * 128, As, Bs);
}

template<int EPI>
__global__ __launch_bounds__(256) void upproj_kernel(
    const bf16* __restrict__ Ckv, const bf16* __restrict__ W, bf16* __restrict__ Out)
{
  __shared__ bf16 As[128 * 32];
  __shared__ bf16 Bs[128 * 32];
  const int z = blockIdx.y, b = z / Hc, h = z % Hc;
  const bf16* A = Ckv + (size_t)b * Sc * DLc;
  const bf16* BT = W + (size_t)h * DHc * DLc;
  if (EPI == 0) {
    bf16* C = Out + (size_t)z * Sc * DHc;
    gemm_tile_128<0>(A, BT, C, DLc, DHc, blockIdx.x * 128, 0, As, Bs);
  } else {
    bf16* C = Out + (size_t)z * DHc * Sc;
    gemm_tile_128<1>(A, BT, C, DLc, Sc, blockIdx.x * 128, 0, As, Bs);
  }
}

// ---------------------------------------------------------------------------
// Flash attention, pipelined LDS-staged K/V (double-buffered, XOR-swizzled)
// + defer-max online softmax (T13).
// 8 waves/block, 32 q-rows/wave. KV tile = 64.
// ---------------------------------------------------------------------------
constexpr int KVB = 64;
constexpr int NTT = Sc / KVB;   // 32 tiles

__global__ __launch_bounds__(512, 2) void mla_attn_kernel(
    const bf16* __restrict__ Q, const bf16* __restrict__ Kup,
    const bf16* __restrict__ VT, bf16* __restrict__ O)
{
  __shared__ bf16 Ks[2][KVB * DHc];    // 16 KB each
  __shared__ bf16 Vs[2][DHc * KVB];    // 16 KB each
  __shared__ bf16 Pl[8][32][68];       // per-wave P tile, 136B stride (2-way banks)

  const int tid = threadIdx.x, lane = tid & 63, wid = tid >> 6;
  const int h = blockIdx.y, b = blockIdx.z;
  const int q0 = blockIdx.x * 256 + wid * 32;
  const int fr = lane & 15, fg = lane >> 4;

  const bf16* Qp = Q + (size_t)(b * Sc + q0 + fr) * DMc + h * DHc + fg * 8;
  short8v qf[2][4];
#pragma unroll
  for (int mi = 0; mi < 2; ++mi)
#pragma unroll
    for (int kf = 0; kf < 4; ++kf)
      qf[mi][kf] = *(const short8v*)(Qp + (size_t)mi * 16 * DMc + kf * 32);

  const bf16* Kb = Kup + (size_t)(b * Hc + h) * Sc * DHc;   // K[t][d]
  const bf16* Vb = VT + (size_t)(b * Hc + h) * DHc * Sc;    // VT[d][t]

  // staging addresses (inverse-swizzled global sources; LDS dest linear)
  const int krow = wid * 4 + fg;
  const int kcolB = (fr * 16) ^ ((krow & 7) << 4);
  const bf16* kg = Kb + (size_t)krow * DHc + (kcolB >> 1);
  const int vrow = wid * 8 + (lane >> 3);
  const int vcolB = ((lane & 7) * 16) ^ ((lane >> 3) << 4);
  const bf16* vg = Vb + (size_t)vrow * Sc + (vcolB >> 1);

  auto STAGE = [&](int buf, int t0) {
    char* kd = (char*)(&Ks[buf][0]) + wid * 1024;
    const bf16* kp = kg + (size_t)t0 * DHc;
    gload_lds16(kp, kd);
    gload_lds16(kp + (size_t)32 * DHc, kd + 8192);
    char* vd = (char*)(&Vs[buf][0]) + wid * 1024;
    const bf16* vp = vg + t0;
    gload_lds16(vp, vd);
    gload_lds16(vp + (size_t)64 * Sc, vd + 8192);
  };

  f32x4 oacc[2][8] = {};
  float m_r[2][4], l_r[2][4], msc[2][4];
#pragma unroll
  for (int mi = 0; mi < 2; ++mi)
#pragma unroll
    for (int r = 0; r < 4; ++r) {
      m_r[mi][r] = -1e30f; l_r[mi][r] = 0.f; msc[mi][r] = -1e30f;
    }
  const float SCL2 = 0.12751650f;     // (1/sqrt(128)) * log2(e)
  const float THRraw = 47.0f;         // ~6 / SCL2 -> p bounded by 2^6

  STAGE(0, 0);
  int cur = 0;

  for (int it = 0; it < NTT; ++it) {
    if (it + 1 < NTT) {
      STAGE(cur ^ 1, (it + 1) * KVB);
      asm volatile("s_waitcnt vmcnt(4)" ::: "memory");
    } else {
      asm volatile("s_waitcnt vmcnt(0)" ::: "memory");
    }
    __builtin_amdgcn_s_barrier();
    asm volatile("" ::: "memory");

    // ---- QK^T ----
    f32x4 sacc[2][4] = {};
#pragma unroll
    for (int nf = 0; nf < 4; ++nf) {
#pragma unroll
      for (int kf = 0; kf < 4; ++kf) {
        const bf16* kr = &Ks[cur][(nf * 16 + fr) * 128 +
                                  (((kf * 64 + fg * 16) ^ ((fr & 7) << 4)) >> 1)];
        short8v kfrag = *(const short8v*)kr;
        sacc[0][nf] = MFMA_16x16x32(qf[0][kf], kfrag, sacc[0][nf]);
        sacc[1][nf] = MFMA_16x16x32(qf[1][kf], kfrag, sacc[1][nf]);
      }
    }

    // ---- online softmax with defer-max ----
    float pmax[2][4];
    float dmax = -1e30f;
#pragma unroll
    for (int mi = 0; mi < 2; ++mi)
#pragma unroll
      for (int r = 0; r < 4; ++r) {
        pmax[mi][r] = fmaxf(fmaxf(sacc[mi][0][r], sacc[mi][1][r]),
                            fmaxf(sacc[mi][2][r], sacc[mi][3][r]));
        dmax = fmaxf(dmax, pmax[mi][r] - m_r[mi][r]);
      }

    if (!__all(dmax <= THRraw)) {
      // full rescale path (rare after warm-up)
#pragma unroll
      for (int mi = 0; mi < 2; ++mi) {
        f32x4 corrv;
#pragma unroll
        for (int r = 0; r < 4; ++r) {
          float red = pmax[mi][r];
#pragma unroll
          for (int mk = 1; mk < 16; mk <<= 1)
            red = fmaxf(red, __shfl_xor(red, mk, 64));
          float mnew = fmaxf(m_r[mi][r], red);
          float c = exp2f((m_r[mi][r] - mnew) * SCL2);
          m_r[mi][r] = mnew;
          msc[mi][r] = mnew * SCL2;
          l_r[mi][r] *= c;
          corrv[r] = c;
        }
#pragma unroll
        for (int df = 0; df < 8; ++df) oacc[mi][df] *= corrv;
      }
    }

    // P compute + write (common path)
#pragma unroll
    for (int mi = 0; mi < 2; ++mi)
#pragma unroll
      for (int nf = 0; nf < 4; ++nf)
#pragma unroll
        for (int r = 0; r < 4; ++r) {
          float p = exp2f(__builtin_fmaf(sacc[mi][nf][r], SCL2, -msc[mi][r]));
          l_r[mi][r] += p;
          Pl[wid][mi * 16 + fg * 4 + r][nf * 16 + fr] = __float2bfloat16(p);
        }

    // wave-local D-layout -> A-layout P roundtrip
    asm volatile("s_waitcnt lgkmcnt(0)" ::: "memory");
    __builtin_amdgcn_sched_barrier(0);

    short8v pa[2][2];
#pragma unroll
    for (int mi = 0; mi < 2; ++mi)
#pragma unroll
      for (int tf = 0; tf < 2; ++tf) {
        const bf16* pr = &Pl[wid][mi * 16 + fr][tf * 32 + fg * 8];
        short4v lo = *(const short4v*)pr;
        short4v hi = *(const short4v*)(pr + 4);
        pa[mi][tf] = __builtin_shufflevector(lo, hi, 0, 1, 2, 3, 4, 5, 6, 7);
      }

    // ---- PV ----
#pragma unroll
    for (int tf = 0; tf < 2; ++tf) {
#pragma unroll
      for (int df = 0; df < 8; ++df) {
        const bf16* vr = &Vs[cur][(df * 16 + fr) * 64 +
                                  (((tf * 64 + fg * 16) ^ ((fr & 7) << 4)) >> 1)];
        short8v vfrag = *(const short8v*)vr;
        oacc[0][df] = MFMA_16x16x32(pa[0][tf], vfrag, oacc[0][df]);
        oacc[1][df] = MFMA_16x16x32(pa[1][tf], vfrag, oacc[1][df]);
      }
    }

    __builtin_amdgcn_s_barrier();
    asm volatile("" ::: "memory");
    cur ^= 1;
  }

  // epilogue
#pragma unroll
  for (int mi = 0; mi < 2; ++mi) {
    float inv[4];
#pragma unroll
    for (int r = 0; r < 4; ++r) {
      float l = l_r[mi][r];
#pragma unroll
      for (int mk = 1; mk < 16; mk <<= 1)
        l += __shfl_xor(l, mk, 64);
      inv[r] = 1.f / l;
    }
    bf16* Op = O + (size_t)(b * Sc + q0 + mi * 16 + fg * 4) * DMc + h * DHc + fr;
#pragma unroll
    for (int df = 0; df < 8; ++df)
#pragma unroll
      for (int r = 0; r < 4; ++r)
        Op[(size_t)r * DMc + df * 16] = __float2bfloat16(oacc[mi][df][r] * inv[r]);
  }
}

// ---------------------------------------------------------------------------
extern "C" void kernel_launch(void* const* d_in, const int* in_sizes, int n_in,
                              void* d_out, int out_size, void* d_ws, size_t ws_size,
                              hipStream_t stream)
{
  const float* x    = (const float*)d_in[0];
  const float* Wq   = (const float*)d_in[1];
  const float* Wdkv = (const float*)d_in[2];
  const float* Wuk  = (const float*)d_in[3];
  const float* Wuv  = (const float*)d_in[4];
  const float* Wo   = (const float*)d_in[5];
  float* out = (float*)d_out;

  char* ws = (char*)d_ws;
  bf16* Qb    = (bf16*)(ws + 0);              // 16 MB
  bf16* Kup   = (bf16*)(ws + 16777216);       // 16 MB
  bf16* VTb   = (bf16*)(ws + 33554432);       // 16 MB
  bf16* xb    = (bf16*)(ws + 50331648);       // 16 MB
  bf16* AO    = (bf16*)(ws + 50331648);       // overlay (xb dead by then)
  bf16* Ck    = (bf16*)(ws + 67108864);       //  4 MB
  bf16* Wqb   = (bf16*)(ws + 71303168);       //  8 MB
  bf16* Wdkvb = (bf16*)(ws + 79691776);       //  2 MB
  bf16* Wukb  = (bf16*)(ws + 81788928);       //  2 MB
  bf16* Wuvb  = (bf16*)(ws + 83886080);       //  2 MB
  bf16* Wob   = (bf16*)(ws + 85983232);       //  8 MB

  dim3 blk(256, 1, 1);

  const int nx = Bc * Sc * DMc, nwq = DMc * DMc, nwd = DLc * DMc,
            nwu = Hc * DHc * DLc;
  cvt_f32_bf16_kernel<<<1024, blk, 0, stream>>>(x, xb, nx);
  cvt_f32_bf16_kernel<<<1024, blk, 0, stream>>>(Wq, Wqb, nwq);
  cvt_f32_bf16_kernel<<<512, blk, 0, stream>>>(Wdkv, Wdkvb, nwd);
  cvt_f32_bf16_kernel<<<512, blk, 0, stream>>>(Wuk, Wukb, nwu);
  cvt_f32_bf16_kernel<<<512, blk, 0, stream>>>(Wuv, Wuvb, nwu);
  cvt_f32_bf16_kernel<<<1024, blk, 0, stream>>>(Wo, Wob, nwq);

  gemm_bt_kernel<0><<<dim3(DMc / 128, (Bc * Sc) / 128), blk, 0, stream>>>(xb, Wqb, Qb, DMc, DMc);
  gemm_bt_kernel<0><<<dim3(DLc / 128, (Bc * Sc) / 128), blk, 0, stream>>>(xb, Wdkvb, Ck, DMc, DLc);
  upproj_kernel<0><<<dim3(Sc / 128, Bc * Hc), blk, 0, stream>>>(Ck, Wukb, Kup);
  upproj_kernel<1><<<dim3(Sc / 128, Bc * Hc), blk, 0, stream>>>(Ck, Wuvb, VTb);

  mla_attn_kernel<<<dim3(Sc / 256, Hc, Bc), dim3(512, 1, 1), 0, stream>>>(Qb, Kup, VTb, AO);

  gemm_bt_kernel<2><<<dim3(DMc / 128, (Bc * Sc) / 128), blk, 0, stream>>>(AO, Wob, out, DMc, DMc);
}

// Round 6
// 266.321 us; speedup vs baseline: 3.2176x; 1.1774x over previous
//
#include <hip/hip_runtime.h>
#include <hip/hip_bf16.h>

typedef __hip_bfloat16 bf16;
typedef __attribute__((ext_vector_type(8))) short short8v;
typedef __attribute__((ext_vector_type(4))) short short4v;
typedef __attribute__((ext_vector_type(4))) float f32x4;

#define MFMA_16x16x32(a, b, c) __builtin_amdgcn_mfma_f32_16x16x32_bf16((a), (b), (c), 0, 0, 0)

constexpr int Bc = 2, Sc = 2048, DMc = 2048, Hc = 16, DLc = 512, DHc = 128;

__device__ __forceinline__ void gload_lds16(const bf16* g, void* lds) {
  __builtin_amdgcn_global_load_lds(
      (const __attribute__((address_space(1))) void*)g,
      (__attribute__((address_space(3))) void*)lds, 16, 0, 0);
}

__device__ __forceinline__ unsigned short bf16bits(float f) {
  return __builtin_bit_cast(unsigned short, __float2bfloat16(f));
}

// ---------------------------------------------------------------------------
// fp32 -> bf16 conversion over 6 segments, one launch
// ---------------------------------------------------------------------------
struct CvtArgs {
  const float* src[6];
  bf16* dst[6];
  unsigned int cum[6];     // cumulative start (in 4-elem chunks)
  unsigned int total4;
};

__global__ __launch_bounds__(256) void cvt_all_kernel(CvtArgs a)
{
  unsigned int i = blockIdx.x * 256 + threadIdx.x;
  const unsigned int stride = gridDim.x * 256;
  for (; i < a.total4; i += stride) {
    int s = 0;
#pragma unroll
    for (int k = 1; k < 6; ++k) s += (i >= a.cum[k]) ? 1 : 0;
    unsigned int off = (i - a.cum[s]) * 4;
    float4 v = *(const float4*)(a.src[s] + off);
    short4v p;
    p[0] = (short)bf16bits(v.x);
    p[1] = (short)bf16bits(v.y);
    p[2] = (short)bf16bits(v.z);
    p[3] = (short)bf16bits(v.w);
    *(short4v*)(a.dst[s] + off) = p;
  }
}

// ---------------------------------------------------------------------------
// Generic 128x128 tile GEMM, BK=32, C = A * BT^T. EPI: 0 bf16 C, 1 bf16 C^T,
// 2 fp32 C.
// ---------------------------------------------------------------------------
template<int EPI>
__device__ __forceinline__ void gemm_tile_128(
    const bf16* __restrict__ A, const bf16* __restrict__ BT, void* __restrict__ Cv,
    int K, int ldc, int row0, int col0, bf16* As, bf16* Bs)
{
  const int tid = threadIdx.x;
  const int lane = tid & 63, wid = tid >> 6;
  const int wr = wid >> 1, wc = wid & 1;

  f32x4 acc[4][4] = {};

  const int srow = tid >> 2;
  const int scol = (tid & 3) * 8;
  const bf16* Ag = A + (size_t)(row0 + srow) * K + scol;
  const bf16* Bg = BT + (size_t)(col0 + srow) * K + scol;
  char* AsW = (char*)As + wid * 1024;
  char* BsW = (char*)Bs + wid * 1024;

  const int fr = lane & 15, fk = (lane >> 4) * 8;
  const bf16* aRd = As + (wr * 64 + fr) * 32 + fk;
  const bf16* bRd = Bs + (wc * 64 + fr) * 32 + fk;

  for (int k0 = 0; k0 < K; k0 += 32) {
    gload_lds16(Ag, AsW);
    gload_lds16(Ag + (size_t)64 * K, AsW + 4096);
    gload_lds16(Bg, BsW);
    gload_lds16(Bg + (size_t)64 * K, BsW + 4096);
    Ag += 32; Bg += 32;
    __syncthreads();
    short8v a[4], b[4];
#pragma unroll
    for (int m = 0; m < 4; ++m) a[m] = *(const short8v*)(aRd + m * 16 * 32);
#pragma unroll
    for (int n = 0; n < 4; ++n) b[n] = *(const short8v*)(bRd + n * 16 * 32);
#pragma unroll
    for (int m = 0; m < 4; ++m)
#pragma unroll
      for (int n = 0; n < 4; ++n)
        acc[m][n] = MFMA_16x16x32(a[m], b[n], acc[m][n]);
    __syncthreads();
  }

  const int crow = (lane >> 4) * 4, ccol = lane & 15;
  if (EPI == 0) {
    bf16* C = (bf16*)Cv;
#pragma unroll
    for (int m = 0; m < 4; ++m)
#pragma unroll
      for (int n = 0; n < 4; ++n) {
        bf16* Cp = C + (size_t)(row0 + wr * 64 + m * 16 + crow) * ldc
                     + col0 + wc * 64 + n * 16 + ccol;
#pragma unroll
        for (int r = 0; r < 4; ++r)
          Cp[(size_t)r * ldc] = __float2bfloat16(acc[m][n][r]);
      }
  } else if (EPI == 1) {
    bf16* C = (bf16*)Cv;
#pragma unroll
    for (int m = 0; m < 4; ++m)
#pragma unroll
      for (int n = 0; n < 4; ++n) {
        short4v pk;
#pragma unroll
        for (int r = 0; r < 4; ++r)
          pk[r] = (short)bf16bits(acc[m][n][r]);
        bf16* Cp = C + (size_t)(col0 + wc * 64 + n * 16 + ccol) * ldc
                     + row0 + wr * 64 + m * 16 + crow;
        *(short4v*)Cp = pk;
      }
  } else {
    float* C = (float*)Cv;
#pragma unroll
    for (int m = 0; m < 4; ++m)
#pragma unroll
      for (int n = 0; n < 4; ++n) {
        float* Cp = C + (size_t)(row0 + wr * 64 + m * 16 + crow) * ldc
                      + col0 + wc * 64 + n * 16 + ccol;
#pragma unroll
        for (int r = 0; r < 4; ++r)
          Cp[(size_t)r * ldc] = acc[m][n][r];
      }
  }
}

template<int EPI>
__global__ __launch_bounds__(256) void gemm_bt_kernel(
    const bf16* __restrict__ A, const bf16* __restrict__ BT, void* __restrict__ C,
    int K, int N)
{
  __shared__ bf16 As[128 * 32];
  __shared__ bf16 Bs[128 * 32];
  gemm_tile_128<EPI>(A, BT, C, K, N, blockIdx.y * 128, blockIdx.x * 128, As, Bs);
}

// Fused Q-proj + KV-down: N = 2048 (Wq) + 512 (Wdkv), K = 2048.
__global__ __launch_bounds__(256) void qkv_gemm_kernel(
    const bf16* __restrict__ xb, const bf16* __restrict__ Wqb,
    const bf16* __restrict__ Wdkvb, bf16* __restrict__ Qb, bf16* __restrict__ Ck)
{
  __shared__ bf16 As[128 * 32];
  __shared__ bf16 Bs[128 * 32];
  const int bx = blockIdx.x, row0 = blockIdx.y * 128;
  if (bx < 16)
    gemm_tile_128<0>(xb, Wqb, Qb, DMc, DMc, row0, bx * 128, As, Bs);
  else
    gemm_tile_128<0>(xb, Wdkvb, Ck, DMc, DLc, row0, (bx - 16) * 128, As, Bs);
}

// Fused K-up + V-up as ONE GEMM over stacked heads:
//   Wuk flat (H*DH, DL) is already B^T. K stored (B*S, H*DH);
//   V stored transposed (H*DH, B*S). M=4096, N=4096, K=512.
__global__ __launch_bounds__(256) void up_gemm_kernel(
    const bf16* __restrict__ Ck, const bf16* __restrict__ Wukb,
    const bf16* __restrict__ Wuvb, bf16* __restrict__ Kcat, bf16* __restrict__ VTcat)
{
  __shared__ bf16 As[128 * 32];
  __shared__ bf16 Bs[128 * 32];
  const int bx = blockIdx.x, row0 = blockIdx.y * 128;
  if (bx < 16)
    gemm_tile_128<0>(Ck, Wukb, Kcat, DLc, DMc, row0, bx * 128, As, Bs);
  else
    gemm_tile_128<1>(Ck, Wuvb, VTcat, DLc, Bc * Sc, row0, (bx - 16) * 128, As, Bs);
}

// ---------------------------------------------------------------------------
// Flash attention, pipelined LDS-staged K/V (double-buffered, XOR-swizzled)
// + defer-max softmax + setprio. LDS = 81920 B -> 2 blocks/CU.
// K rows from Kcat (stride DMc); V^T rows from VTcat (stride B*S).
// P roundtrip: per-wave [16][64] swizzled buffer, two sequential mi-passes.
// ---------------------------------------------------------------------------
constexpr int KVB = 64;
constexpr int NTT = Sc / KVB;   // 32 tiles
constexpr int VSTR = Bc * Sc;   // 4096

__global__ __launch_bounds__(512, 2) void mla_attn_kernel(
    const bf16* __restrict__ Q, const bf16* __restrict__ Kcat,
    const bf16* __restrict__ VTcat, bf16* __restrict__ O)
{
  __shared__ bf16 Ks[2][KVB * DHc];    // 16 KB each
  __shared__ bf16 Vs[2][DHc * KVB];    // 16 KB each
  __shared__ bf16 Pl[8][16][64];       // per-wave swizzled P buffer (16 KB)

  const int tid = threadIdx.x, lane = tid & 63, wid = tid >> 6;
  const int h = blockIdx.y, b = blockIdx.z;
  const int q0 = blockIdx.x * 256 + wid * 32;
  const int fr = lane & 15, fg = lane >> 4;

  const bf16* Qp = Q + (size_t)(b * Sc + q0 + fr) * DMc + h * DHc + fg * 8;
  short8v qf[2][4];
#pragma unroll
  for (int mi = 0; mi < 2; ++mi)
#pragma unroll
    for (int kf = 0; kf < 4; ++kf)
      qf[mi][kf] = *(const short8v*)(Qp + (size_t)mi * 16 * DMc + kf * 32);

  const bf16* Kb = Kcat + (size_t)b * Sc * DMc + h * DHc;      // K[t][d], stride DMc
  const bf16* Vb = VTcat + (size_t)(h * DHc) * VSTR + b * Sc;  // VT[d][t], stride VSTR

  // staging addresses (inverse-swizzled global sources; LDS dest linear)
  const int krow = wid * 4 + fg;
  const int kcolB = (fr * 16) ^ ((krow & 7) << 4);
  const bf16* kg = Kb + (size_t)krow * DMc + (kcolB >> 1);
  const int vrow = wid * 8 + (lane >> 3);
  const int vcolB = ((lane & 7) * 16) ^ ((lane >> 3) << 4);
  const bf16* vg = Vb + (size_t)vrow * VSTR + (vcolB >> 1);

  auto STAGE = [&](int buf, int t0) {
    char* kd = (char*)(&Ks[buf][0]) + wid * 1024;
    const bf16* kp = kg + (size_t)t0 * DMc;
    gload_lds16(kp, kd);
    gload_lds16(kp + (size_t)32 * DMc, kd + 8192);
    char* vd = (char*)(&Vs[buf][0]) + wid * 1024;
    const bf16* vp = vg + t0;
    gload_lds16(vp, vd);
    gload_lds16(vp + (size_t)64 * VSTR, vd + 8192);
  };

  f32x4 oacc[2][8] = {};
  float m_r[2][4], l_r[2][4], msc[2][4];
#pragma unroll
  for (int mi = 0; mi < 2; ++mi)
#pragma unroll
    for (int r = 0; r < 4; ++r) {
      m_r[mi][r] = -1e30f; l_r[mi][r] = 0.f; msc[mi][r] = -1e30f;
    }
  const float SCL2 = 0.12751650f;     // (1/sqrt(128)) * log2(e)
  const float THRraw = 47.0f;         // ~6 / SCL2 -> p bounded by 2^6

  STAGE(0, 0);
  int cur = 0;
  char* Pw = (char*)(&Pl[wid][0][0]);

  for (int it = 0; it < NTT; ++it) {
    if (it + 1 < NTT) {
      STAGE(cur ^ 1, (it + 1) * KVB);
      asm volatile("s_waitcnt vmcnt(4)" ::: "memory");
    } else {
      asm volatile("s_waitcnt vmcnt(0)" ::: "memory");
    }
    __builtin_amdgcn_s_barrier();
    asm volatile("" ::: "memory");

    // ---- QK^T ----
    f32x4 sacc[2][4] = {};
    __builtin_amdgcn_s_setprio(1);
#pragma unroll
    for (int nf = 0; nf < 4; ++nf) {
#pragma unroll
      for (int kf = 0; kf < 4; ++kf) {
        const bf16* kr = &Ks[cur][(nf * 16 + fr) * 128 +
                                  (((kf * 64 + fg * 16) ^ ((fr & 7) << 4)) >> 1)];
        short8v kfrag = *(const short8v*)kr;
        sacc[0][nf] = MFMA_16x16x32(qf[0][kf], kfrag, sacc[0][nf]);
        sacc[1][nf] = MFMA_16x16x32(qf[1][kf], kfrag, sacc[1][nf]);
      }
    }
    __builtin_amdgcn_s_setprio(0);

    // ---- online softmax with defer-max ----
    float pmax[2][4];
    float dmax = -1e30f;
#pragma unroll
    for (int mi = 0; mi < 2; ++mi)
#pragma unroll
      for (int r = 0; r < 4; ++r) {
        pmax[mi][r] = fmaxf(fmaxf(sacc[mi][0][r], sacc[mi][1][r]),
                            fmaxf(sacc[mi][2][r], sacc[mi][3][r]));
        dmax = fmaxf(dmax, pmax[mi][r] - m_r[mi][r]);
      }

    if (!__all(dmax <= THRraw)) {
#pragma unroll
      for (int mi = 0; mi < 2; ++mi) {
        f32x4 corrv;
#pragma unroll
        for (int r = 0; r < 4; ++r) {
          float red = pmax[mi][r];
#pragma unroll
          for (int mk = 1; mk < 16; mk <<= 1)
            red = fmaxf(red, __shfl_xor(red, mk, 64));
          float mnew = fmaxf(m_r[mi][r], red);
          float c = exp2f((m_r[mi][r] - mnew) * SCL2);
          m_r[mi][r] = mnew;
          msc[mi][r] = mnew * SCL2;
          l_r[mi][r] *= c;
          corrv[r] = c;
        }
#pragma unroll
        for (int df = 0; df < 8; ++df) oacc[mi][df] *= corrv;
      }
    }

    // ---- P compute + per-mi LDS roundtrip (per-wave private buffer) ----
    short8v pa[2][2];
#pragma unroll
    for (int mi = 0; mi < 2; ++mi) {
#pragma unroll
      for (int nf = 0; nf < 4; ++nf)
#pragma unroll
        for (int r = 0; r < 4; ++r) {
          float p = exp2f(__builtin_fmaf(sacc[mi][nf][r], SCL2, -msc[mi][r]));
          l_r[mi][r] += p;
          const int row = fg * 4 + r;
          const int cb = (nf * 32 + fr * 2) ^ ((row & 7) << 4);
          *(bf16*)(Pw + row * 128 + cb) = __float2bfloat16(p);
        }
      asm volatile("s_waitcnt lgkmcnt(0)" ::: "memory");
      __builtin_amdgcn_sched_barrier(0);
      const int rb0 = fr * 128 + ((fg * 16) ^ ((fr & 7) << 4));
      const int rb1 = fr * 128 + ((64 + fg * 16) ^ ((fr & 7) << 4));
      pa[mi][0] = *(const short8v*)(Pw + rb0);
      pa[mi][1] = *(const short8v*)(Pw + rb1);
      __builtin_amdgcn_sched_barrier(0);
    }

    // ---- PV ----
    __builtin_amdgcn_s_setprio(1);
#pragma unroll
    for (int tf = 0; tf < 2; ++tf) {
#pragma unroll
      for (int df = 0; df < 8; ++df) {
        const bf16* vr = &Vs[cur][(df * 16 + fr) * 64 +
                                  (((tf * 64 + fg * 16) ^ ((fr & 7) << 4)) >> 1)];
        short8v vfrag = *(const short8v*)vr;
        oacc[0][df] = MFMA_16x16x32(pa[0][tf], vfrag, oacc[0][df]);
        oacc[1][df] = MFMA_16x16x32(pa[1][tf], vfrag, oacc[1][df]);
      }
    }
    __builtin_amdgcn_s_setprio(0);

    __builtin_amdgcn_s_barrier();
    asm volatile("" ::: "memory");
    cur ^= 1;
  }

  // epilogue
#pragma unroll
  for (int mi = 0; mi < 2; ++mi) {
    float inv[4];
#pragma unroll
    for (int r = 0; r < 4; ++r) {
      float l = l_r[mi][r];
#pragma unroll
      for (int mk = 1; mk < 16; mk <<= 1)
        l += __shfl_xor(l, mk, 64);
      inv[r] = 1.f / l;
    }
    bf16* Op = O + (size_t)(b * Sc + q0 + mi * 16 + fg * 4) * DMc + h * DHc + fr;
#pragma unroll
    for (int df = 0; df < 8; ++df)
#pragma unroll
      for (int r = 0; r < 4; ++r)
        Op[(size_t)r * DMc + df * 16] = __float2bfloat16(oacc[mi][df][r] * inv[r]);
  }
}

// ---------------------------------------------------------------------------
extern "C" void kernel_launch(void* const* d_in, const int* in_sizes, int n_in,
                              void* d_out, int out_size, void* d_ws, size_t ws_size,
                              hipStream_t stream)
{
  const float* x    = (const float*)d_in[0];
  const float* Wq   = (const float*)d_in[1];
  const float* Wdkv = (const float*)d_in[2];
  const float* Wuk  = (const float*)d_in[3];
  const float* Wuv  = (const float*)d_in[4];
  const float* Wo   = (const float*)d_in[5];
  float* out = (float*)d_out;

  char* ws = (char*)d_ws;
  bf16* Qb    = (bf16*)(ws + 0);              // 16 MB
  bf16* Kcat  = (bf16*)(ws + 16777216);       // 16 MB  (B*S, H*DH)
  bf16* VTcat = (bf16*)(ws + 33554432);       // 16 MB  (H*DH, B*S)
  bf16* xb    = (bf16*)(ws + 50331648);       // 16 MB
  bf16* AO    = (bf16*)(ws + 50331648);       // overlay (xb dead by then)
  bf16* Ck    = (bf16*)(ws + 67108864);       //  4 MB
  bf16* Wqb   = (bf16*)(ws + 71303168);       //  8 MB
  bf16* Wdkvb = (bf16*)(ws + 79691776);       //  2 MB
  bf16* Wukb  = (bf16*)(ws + 81788928);       //  2 MB
  bf16* Wuvb  = (bf16*)(ws + 83886080);       //  2 MB
  bf16* Wob   = (bf16*)(ws + 85983232);       //  8 MB

  dim3 blk(256, 1, 1);

  // one fused fp32->bf16 conversion pass
  CvtArgs ca;
  ca.src[0] = x;    ca.dst[0] = xb;
  ca.src[1] = Wq;   ca.dst[1] = Wqb;
  ca.src[2] = Wdkv; ca.dst[2] = Wdkvb;
  ca.src[3] = Wuk;  ca.dst[3] = Wukb;
  ca.src[4] = Wuv;  ca.dst[4] = Wuvb;
  ca.src[5] = Wo;   ca.dst[5] = Wob;
  unsigned int n4[6] = { (unsigned)(Bc * Sc * DMc / 4), (unsigned)(DMc * DMc / 4),
                         (unsigned)(DLc * DMc / 4),     (unsigned)(Hc * DHc * DLc / 4),
                         (unsigned)(Hc * DHc * DLc / 4),(unsigned)(DMc * DMc / 4) };
  unsigned int acc = 0;
  for (int i = 0; i < 6; ++i) { ca.cum[i] = acc; acc += n4[i]; }
  ca.total4 = acc;
  cvt_all_kernel<<<2048, blk, 0, stream>>>(ca);

  // Q = x@Wq^T and Ckv = x@Wdkv^T, one launch (N = 2048 + 512)
  qkv_gemm_kernel<<<dim3(20, (Bc * Sc) / 128), blk, 0, stream>>>(xb, Wqb, Wdkvb, Qb, Ck);

  // K/V up-projections as one M=4096, N=4096, K=512 GEMM
  up_gemm_kernel<<<dim3(32, (Bc * Sc) / 128), blk, 0, stream>>>(Ck, Wukb, Wuvb, Kcat, VTcat);

  // attention
  mla_attn_kernel<<<dim3(Sc / 256, Hc, Bc), dim3(512, 1, 1), 0, stream>>>(Qb, Kcat, VTcat, AO);

  // out = AO @ Wo^T (fp32 out)
  gemm_bt_kernel<2><<<dim3(DMc / 128, (Bc * Sc) / 128), blk, 0, stream>>>(AO, Wob, out, DMc, DMc);
}